// Round 9
// baseline (3380.295 us; speedup 1.0000x reference)
//
#include <hip/hip_runtime.h>
#include <hip/hip_bf16.h>

#define BATCH 64
#define HID 512
#define EMB 256
#define VOCAB 32000
#define G4 2048   // 4*HID

typedef __attribute__((ext_vector_type(8))) short short8;
typedef __attribute__((ext_vector_type(4))) float f32x4;

// ---------------- zero init ----------------
__global__ __launch_bounds__(256) void zero_kernel(float* p, int n){
    int i = blockIdx.x*256 + threadIdx.x;
    if (i < n) p[i] = 0.f;
}

// ---------------- embedding gather ----------------
__global__ __launch_bounds__(256) void embed_kernel(const int* __restrict__ tok,
                                                    const float* __restrict__ emb,
                                                    float* __restrict__ out, int T){
    int i = blockIdx.x*256 + threadIdx.x;
    int n = T*BATCH*(EMB/4);
    if (i >= n) return;
    int e4 = i % (EMB/4);
    int tb = i / (EMB/4);
    int id = tok[tb];
    reinterpret_cast<float4*>(out)[(size_t)tb*(EMB/4) + e4] =
        reinterpret_cast<const float4*>(emb + (size_t)id*EMB)[e4];
}

// round-to-nearest-even fp32 -> bf16 bits
__device__ __forceinline__ unsigned short bf16_rne(float x){
    unsigned b = __float_as_uint(x);
    return (unsigned short)((b + 0x7fffu + ((b >> 16) & 1u)) >> 16);
}

// ---------------- MFMA split-bf16 GEMM (unchanged) ----------------
template<int KDIM, int NDIM>
__global__ __launch_bounds__(256) void gemm_mfma_split(
    const float* __restrict__ A, const float* __restrict__ B,
    const float* __restrict__ bias, float* __restrict__ C, int M)
{
    constexpr int LS = 40;
    __shared__ unsigned short Ah[128*LS], Al[128*LS], Bh[128*LS], Bl[128*LS];
    const int n0 = blockIdx.x*128, m0 = blockIdx.y*128;
    const int tid  = threadIdx.x;
    const int lane = tid & 63, wid = tid >> 6;
    const int wm = wid >> 1, wn = wid & 1;
    const int srow = tid >> 1, sk = (tid & 1)*16;
    f32x4 acc[4][4] = {};

    for (int k0 = 0; k0 < KDIM; k0 += 32){
        __syncthreads();
        {
            int ar = m0 + srow;
            float xv[16];
            if (ar < M){
                const float4* ap = reinterpret_cast<const float4*>(A + (size_t)ar*KDIM + k0 + sk);
                #pragma unroll
                for (int q = 0; q < 4; q++){
                    float4 v = ap[q];
                    xv[q*4+0]=v.x; xv[q*4+1]=v.y; xv[q*4+2]=v.z; xv[q*4+3]=v.w;
                }
            } else {
                #pragma unroll
                for (int q = 0; q < 16; q++) xv[q] = 0.f;
            }
            #pragma unroll
            for (int q = 0; q < 16; q++){
                unsigned short h = bf16_rne(xv[q]);
                float hf = __uint_as_float((unsigned)h << 16);
                Ah[srow*LS + sk + q] = h;
                Al[srow*LS + sk + q] = bf16_rne(xv[q] - hf);
            }
        }
        {
            int br = n0 + srow;
            const float4* bp = reinterpret_cast<const float4*>(B + (size_t)br*KDIM + k0 + sk);
            #pragma unroll
            for (int q = 0; q < 4; q++){
                float4 v = bp[q];
                float xs[4] = {v.x, v.y, v.z, v.w};
                #pragma unroll
                for (int j = 0; j < 4; j++){
                    unsigned short h = bf16_rne(xs[j]);
                    float hf = __uint_as_float((unsigned)h << 16);
                    Bh[srow*LS + sk + q*4 + j] = h;
                    Bl[srow*LS + sk + q*4 + j] = bf16_rne(xs[j] - hf);
                }
            }
        }
        __syncthreads();
        const int fr = lane & 15, fk = (lane >> 4)*8;
        short8 a_h[4], a_l[4], b_h[4], b_l[4];
        #pragma unroll
        for (int mi = 0; mi < 4; mi++){
            int row = wm*64 + mi*16 + fr;
            a_h[mi] = *reinterpret_cast<const short8*>(&Ah[row*LS + fk]);
            a_l[mi] = *reinterpret_cast<const short8*>(&Al[row*LS + fk]);
        }
        #pragma unroll
        for (int nj = 0; nj < 4; nj++){
            int rowb = wn*64 + nj*16 + fr;
            b_h[nj] = *reinterpret_cast<const short8*>(&Bh[rowb*LS + fk]);
            b_l[nj] = *reinterpret_cast<const short8*>(&Bl[rowb*LS + fk]);
        }
        #pragma unroll
        for (int mi = 0; mi < 4; mi++)
            #pragma unroll
            for (int nj = 0; nj < 4; nj++){
                acc[mi][nj] = __builtin_amdgcn_mfma_f32_16x16x32_bf16(a_h[mi], b_h[nj], acc[mi][nj], 0,0,0);
                acc[mi][nj] = __builtin_amdgcn_mfma_f32_16x16x32_bf16(a_h[mi], b_l[nj], acc[mi][nj], 0,0,0);
                acc[mi][nj] = __builtin_amdgcn_mfma_f32_16x16x32_bf16(a_l[mi], b_h[nj], acc[mi][nj], 0,0,0);
            }
    }
    const int fr = lane & 15, fq = lane >> 4;
    #pragma unroll
    for (int nj = 0; nj < 4; nj++){
        int col = n0 + wn*64 + nj*16 + fr;
        float bv = bias[col];
        #pragma unroll
        for (int mi = 0; mi < 4; mi++){
            int rbase = m0 + wm*64 + mi*16 + fq*4;
            #pragma unroll
            for (int j = 0; j < 4; j++){
                int row = rbase + j;
                if (row < M)
                    __builtin_nontemporal_store(acc[mi][nj][j] + bv, &C[(size_t)row*NDIM + col]);
            }
        }
    }
}

// ---------------- persistent LSTM layer ----------------
// 256 blocks x 256 threads. Block (hc=bx&31, bc=bx>>5): 16 hid x 8 batch outputs.
// Whh slice register-resident.
// h exchange protocol (fence-free, no uncached READS):
//   WRITE: gate threads put h(t) in LDS; wave 0 lanes 0..31 issue 32 x
//          global_store_dwordx4 sc0 sc1 (bypass L2 -> coherence point, 64B
//          granules), drain vmcnt, then tid0 stores its epoch flag (sc-bypass).
//   READ:  plain CACHED float4 loads. Safe: each ys[t] plane is a fresh address;
//          writes bypass L2, so no cache holds a copy until the first read,
//          which happens only after all 32 writers' flags >= t (writers drained
//          first). Each plane is read in exactly one step -> no stale reuse.
//          Same-XCD group members share the fetched lines via L2.
//   Barrier: per bc-group (32 blocks), per-block epoch flags 64B apart, no RMW;
//          wave-0 lanes poll the 32 flags in parallel (__all). Bounded spin.
__global__ __launch_bounds__(256, 1) void lstm_layer_k(
    const float* __restrict__ Xp,    // [T*64, 2048]
    const float* __restrict__ Whh,   // [2048, 512]
    const float* __restrict__ hinit, // [64, 512]
    const float* __restrict__ cinit, // [64, 512]
    float* __restrict__ ys,          // [T*64, 512]
    float* __restrict__ cfin,        // [64, 512]
    int T,
    unsigned* __restrict__ flagbase) // 8 groups x 32 members x 16 uints, zeroed
{
    __shared__ f32x4 hs4[1024];      // 16 KB h(t-1); first 128 floats reused for h(t) out
    __shared__ float red[4*64*8];    // 8 KB
    float* hs = (float*)hs4;

    const int bx  = blockIdx.x;
    const int hc  = bx & 31, bc = bx >> 5;
    const int hid0 = hc*16;
    const int tid = threadIdx.x;
    const int r   = tid & 63, kc = tid >> 6;
    const int g   = r >> 4, hl = r & 15;
    const int gr  = g*HID + hid0 + hl;
    unsigned* myflag = flagbase + (size_t)(bc*32 + hc)*16;

    float4 w[32];
    {
        const float4* wp = reinterpret_cast<const float4*>(Whh + (size_t)gr*HID) + kc*32;
        #pragma unroll
        for (int j = 0; j < 32; j++) w[j] = wp[j];
    }

    const int ub = tid >> 4;   // batch (tid<128)
    const int uh = tid & 15;   // hid
    float creg = 0.f;
    if (tid < 128) creg = cinit[(size_t)(bc*8 + ub)*HID + hid0 + uh];

    const size_t hbase = (size_t)bc*8*HID;
    const float* xprow = Xp + (size_t)(bc*8 + ub)*G4 + hid0 + uh;  // valid for tid<128

    // prefetch Xp for t=0 (cached)
    float xn0=0.f, xn1=0.f, xn2=0.f, xn3=0.f;
    if (tid < 128){
        const float* xpr = xprow;
        xn0 = xpr[0]; xn1 = xpr[512]; xn2 = xpr[1024]; xn3 = xpr[1536];
    }

    for (int t = 0; t < T; t++){
        // ---- stage h(t-1) into LDS: PLAIN CACHED loads (L2 miss -> L3 hit) ----
        {
            const f32x4* hsrc = reinterpret_cast<const f32x4*>(
                (t == 0) ? (hinit + hbase) : (ys + (size_t)(t-1)*BATCH*HID + hbase));
            f32x4 v0 = hsrc[tid], v1 = hsrc[tid+256], v2 = hsrc[tid+512], v3 = hsrc[tid+768];
            hs4[tid] = v0; hs4[tid+256] = v1; hs4[tid+512] = v2; hs4[tid+768] = v3;
        }
        __syncthreads();

        // ---- partial dots ----
        float4 a4[8];
        #pragma unroll
        for (int b = 0; b < 8; b++) a4[b] = float4{0.f,0.f,0.f,0.f};
        const float4* h4 = reinterpret_cast<const float4*>(hs) + kc*32;
        #pragma unroll
        for (int j = 0; j < 32; j++){
            float4 a = w[j];
            #pragma unroll
            for (int b = 0; b < 8; b++){
                float4 hv = h4[b*128 + j];
                a4[b].x += a.x*hv.x; a4[b].y += a.y*hv.y;
                a4[b].z += a.z*hv.z; a4[b].w += a.w*hv.w;
            }
        }
        #pragma unroll
        for (int b = 0; b < 8; b++)
            red[(kc*64 + r)*8 + b] = a4[b].x + a4[b].y + a4[b].z + a4[b].w;
        __syncthreads();

        if (tid < 64){
            #pragma unroll
            for (int b = 0; b < 8; b++)
                red[tid*8 + b] = red[tid*8 + b] + red[(64+tid)*8 + b]
                               + red[(128+tid)*8 + b] + red[(192+tid)*8 + b];
        }
        __syncthreads();

        // ---- gates + state update; h(t) -> LDS; prefetch next Xp ----
        if (tid < 128){
            float gi = red[(0*16 + uh)*8 + ub] + xn0;
            float gf = red[(1*16 + uh)*8 + ub] + xn1;
            float gg = red[(2*16 + uh)*8 + ub] + xn2;
            float go = red[(3*16 + uh)*8 + ub] + xn3;
            float si = 1.f/(1.f + expf(-gi));
            float sf = 1.f/(1.f + expf(-gf));
            float so = 1.f/(1.f + expf(-go));
            float tg = tanhf(gg);
            float c = sf*creg + si*tg;
            creg = c;
            hs[tid] = so * tanhf(c);       // hs[ub*16+uh]; dot phase done with hs
            if (t < T-1){
                const float* xpr = xprow + (size_t)(t+1)*BATCH*G4;
                xn0 = xpr[0]; xn1 = xpr[512]; xn2 = xpr[1024]; xn3 = xpr[1536];
            }
        }
        __syncthreads();

        // ---- wave 0: vectorized sc-store of h(t), drain, flag, poll ----
        if (tid < 64){
            if (tid < 32){
                f32x4 v = hs4[tid >> 2][0] == 0.f ? hs4[0] : hs4[0]; // (placeholder removed below)
            }
            if (tid < 32){
                f32x4 v;
                v = reinterpret_cast<const f32x4*>(hs)[tid];  // floats 4*tid..4*tid+3
                const f32x4* addr = reinterpret_cast<const f32x4*>(
                    ys + (size_t)t*BATCH*HID
                       + (size_t)(bc*8 + (tid >> 2))*HID + hid0 + (tid & 3)*4);
                asm volatile("global_store_dwordx4 %0, %1, off sc0 sc1"
                             :: "v"(addr), "v"(v) : "memory");
            }
            if (t < T-1){
                asm volatile("s_waitcnt vmcnt(0)" ::: "memory");  // h at coherence point
                if (tid == 0)
                    __hip_atomic_store(myflag, (unsigned)(t+1),
                                       __ATOMIC_RELAXED, __HIP_MEMORY_SCOPE_AGENT);
                const unsigned tgt = (unsigned)(t+1);
                unsigned* fp = flagbase + (size_t)(bc*32 + (tid & 31))*16;
                unsigned spins = 0;
                bool done = false;
                while (!done && spins < (1u<<20)){
                    unsigned v = tgt;
                    if (tid < 32)
                        v = __hip_atomic_load(fp, __ATOMIC_RELAXED, __HIP_MEMORY_SCOPE_AGENT);
                    done = (bool)__all((int)(v >= tgt));
                    spins++;
                }
            }
        }
        __syncthreads();   // all waves wait for poll before next stage
    }

    if (tid < 128)
        cfin[(size_t)(bc*8 + ub)*HID + hid0 + uh] = creg;
}

extern "C" void kernel_launch(void* const* d_in, const int* in_sizes, int n_in,
                              void* d_out, int out_size, void* d_ws, size_t ws_size,
                              hipStream_t stream) {
    const int*   src      = (const int*)  d_in[0];
    const int*   trg      = (const int*)  d_in[1];
    const float* enc_emb  = (const float*)d_in[2];
    const float* enc_Wih0 = (const float*)d_in[3];
    const float* enc_Whh0 = (const float*)d_in[4];
    const float* enc_b0   = (const float*)d_in[5];
    const float* enc_Wih1 = (const float*)d_in[6];
    const float* enc_Whh1 = (const float*)d_in[7];
    const float* enc_b1   = (const float*)d_in[8];
    const float* dec_emb  = (const float*)d_in[9];
    const float* dec_Wih0 = (const float*)d_in[10];
    const float* dec_Whh0 = (const float*)d_in[11];
    const float* dec_b0   = (const float*)d_in[12];
    const float* dec_Wih1 = (const float*)d_in[13];
    const float* dec_Whh1 = (const float*)d_in[14];
    const float* dec_b1   = (const float*)d_in[15];
    const float* out_W    = (const float*)d_in[16];
    const float* out_b    = (const float*)d_in[17];

    // Big transient scratch in d_out (fp32, 100.35M elems); all dead before final GEMM.
    float* ob = (float*)d_out;
    float* Xp   = ob;                         // [3200,2048]
    float* xe   = ob + (size_t)6553600;       // [3200,256]
    float* xd   = ob + (size_t)7372800;       // [3136,256]
    float* eys0 = ob + (size_t)8175616;       // [50*64,512]
    float* eys1 = ob + (size_t)9814016;       // [50*64,512]
    float* dys0 = ob + (size_t)11452416;      // [49*64,512]

    // d_ws: survivors + states + barrier flags (~7 MB).
    float* ws = (float*)d_ws;
    float* dys1 = ws;                              // [49*64,512]
    float* c0   = ws + (size_t)1605632;            // [64,512]
    float* c1   = ws + (size_t)1638400;            // [64,512]
    float* hz   = ws + (size_t)1671168;            // [64,512] zeros
    unsigned* flags = (unsigned*)(ws + (size_t)1703936); // 4 layers x 8 grp x 32 x 16 uints

    // zero c0,c1,hz + flags (re-zeroed every launch -> graph-replay safe)
    {
        int n = 3*BATCH*HID + 4*4096;
        zero_kernel<<<(n+255)/256, 256, 0, stream>>>(c0, n);
    }

    // embeddings
    embed_kernel<<<(50*BATCH*(EMB/4)+255)/256, 256, 0, stream>>>(src, enc_emb, xe, 50);
    embed_kernel<<<(49*BATCH*(EMB/4)+255)/256, 256, 0, stream>>>(trg, dec_emb, xd, 49);

    dim3 xgrid(G4/128, 25);

    // ---- encoder layer 0 ----
    gemm_mfma_split<EMB, G4><<<xgrid, 256, 0, stream>>>(xe, enc_Wih0, enc_b0, Xp, 3200);
    lstm_layer_k<<<256, 256, 0, stream>>>(Xp, enc_Whh0, hz, hz, eys0, c0, 50, flags + 0);

    // ---- encoder layer 1 ----
    gemm_mfma_split<HID, G4><<<xgrid, 256, 0, stream>>>(eys0, enc_Wih1, enc_b1, Xp, 3200);
    lstm_layer_k<<<256, 256, 0, stream>>>(Xp, enc_Whh1, hz, hz, eys1, c1, 50, flags + 4096);

    // ---- decoder layer 0 (h/c continue from encoder layer 0 finals) ----
    gemm_mfma_split<EMB, G4><<<xgrid, 256, 0, stream>>>(xd, dec_Wih0, dec_b0, Xp, 3136);
    lstm_layer_k<<<256, 256, 0, stream>>>(Xp, dec_Whh0, eys0 + (size_t)49*BATCH*HID, c0,
                                          dys0, c0, 49, flags + 8192);

    // ---- decoder layer 1 (h/c continue from encoder layer 1 finals) ----
    gemm_mfma_split<HID, G4><<<xgrid, 256, 0, stream>>>(dys0, dec_Wih1, dec_b1, Xp, 3136);
    lstm_layer_k<<<256, 256, 0, stream>>>(Xp, dec_Whh1, eys1 + (size_t)49*BATCH*HID, c1,
                                          dys1, c1, 49, flags + 12288);

    // ---- final projection -> fp32 d_out [3136, 32000] ----
    gemm_mfma_split<HID, VOCAB><<<dim3(VOCAB/128, 25), 256, 0, stream>>>(
        dys1, out_W, out_b, (float*)d_out, 3136);
}

// Round 10
// 1937.126 us; speedup vs baseline: 1.7450x; 1.7450x over previous
//
#include <hip/hip_runtime.h>
#include <hip/hip_bf16.h>

#define BATCH 64
#define HID 512
#define EMB 256
#define VOCAB 32000
#define G4 2048   // 4*HID

typedef __attribute__((ext_vector_type(8))) short short8;
typedef __attribute__((ext_vector_type(4))) float f32x4;

// ---------------- zero init ----------------
__global__ __launch_bounds__(256) void zero_kernel(float* p, int n){
    int i = blockIdx.x*256 + threadIdx.x;
    if (i < n) p[i] = 0.f;
}

// ---------------- embedding gather ----------------
__global__ __launch_bounds__(256) void embed_kernel(const int* __restrict__ tok,
                                                    const float* __restrict__ emb,
                                                    float* __restrict__ out, int T){
    int i = blockIdx.x*256 + threadIdx.x;
    int n = T*BATCH*(EMB/4);
    if (i >= n) return;
    int e4 = i % (EMB/4);
    int tb = i / (EMB/4);
    int id = tok[tb];
    reinterpret_cast<float4*>(out)[(size_t)tb*(EMB/4) + e4] =
        reinterpret_cast<const float4*>(emb + (size_t)id*EMB)[e4];
}

// round-to-nearest-even fp32 -> bf16 bits
__device__ __forceinline__ unsigned short bf16_rne(float x){
    unsigned b = __float_as_uint(x);
    return (unsigned short)((b + 0x7fffu + ((b >> 16) & 1u)) >> 16);
}

// ---------------- MFMA split-bf16 GEMM (unchanged) ----------------
template<int KDIM, int NDIM>
__global__ __launch_bounds__(256) void gemm_mfma_split(
    const float* __restrict__ A, const float* __restrict__ B,
    const float* __restrict__ bias, float* __restrict__ C, int M)
{
    constexpr int LS = 40;
    __shared__ unsigned short Ah[128*LS], Al[128*LS], Bh[128*LS], Bl[128*LS];
    const int n0 = blockIdx.x*128, m0 = blockIdx.y*128;
    const int tid  = threadIdx.x;
    const int lane = tid & 63, wid = tid >> 6;
    const int wm = wid >> 1, wn = wid & 1;
    const int srow = tid >> 1, sk = (tid & 1)*16;
    f32x4 acc[4][4] = {};

    for (int k0 = 0; k0 < KDIM; k0 += 32){
        __syncthreads();
        {
            int ar = m0 + srow;
            float xv[16];
            if (ar < M){
                const float4* ap = reinterpret_cast<const float4*>(A + (size_t)ar*KDIM + k0 + sk);
                #pragma unroll
                for (int q = 0; q < 4; q++){
                    float4 v = ap[q];
                    xv[q*4+0]=v.x; xv[q*4+1]=v.y; xv[q*4+2]=v.z; xv[q*4+3]=v.w;
                }
            } else {
                #pragma unroll
                for (int q = 0; q < 16; q++) xv[q] = 0.f;
            }
            #pragma unroll
            for (int q = 0; q < 16; q++){
                unsigned short h = bf16_rne(xv[q]);
                float hf = __uint_as_float((unsigned)h << 16);
                Ah[srow*LS + sk + q] = h;
                Al[srow*LS + sk + q] = bf16_rne(xv[q] - hf);
            }
        }
        {
            int br = n0 + srow;
            const float4* bp = reinterpret_cast<const float4*>(B + (size_t)br*KDIM + k0 + sk);
            #pragma unroll
            for (int q = 0; q < 4; q++){
                float4 v = bp[q];
                float xs[4] = {v.x, v.y, v.z, v.w};
                #pragma unroll
                for (int j = 0; j < 4; j++){
                    unsigned short h = bf16_rne(xs[j]);
                    float hf = __uint_as_float((unsigned)h << 16);
                    Bh[srow*LS + sk + q*4 + j] = h;
                    Bl[srow*LS + sk + q*4 + j] = bf16_rne(xs[j] - hf);
                }
            }
        }
        __syncthreads();
        const int fr = lane & 15, fk = (lane >> 4)*8;
        short8 a_h[4], a_l[4], b_h[4], b_l[4];
        #pragma unroll
        for (int mi = 0; mi < 4; mi++){
            int row = wm*64 + mi*16 + fr;
            a_h[mi] = *reinterpret_cast<const short8*>(&Ah[row*LS + fk]);
            a_l[mi] = *reinterpret_cast<const short8*>(&Al[row*LS + fk]);
        }
        #pragma unroll
        for (int nj = 0; nj < 4; nj++){
            int rowb = wn*64 + nj*16 + fr;
            b_h[nj] = *reinterpret_cast<const short8*>(&Bh[rowb*LS + fk]);
            b_l[nj] = *reinterpret_cast<const short8*>(&Bl[rowb*LS + fk]);
        }
        #pragma unroll
        for (int mi = 0; mi < 4; mi++)
            #pragma unroll
            for (int nj = 0; nj < 4; nj++){
                acc[mi][nj] = __builtin_amdgcn_mfma_f32_16x16x32_bf16(a_h[mi], b_h[nj], acc[mi][nj], 0,0,0);
                acc[mi][nj] = __builtin_amdgcn_mfma_f32_16x16x32_bf16(a_h[mi], b_l[nj], acc[mi][nj], 0,0,0);
                acc[mi][nj] = __builtin_amdgcn_mfma_f32_16x16x32_bf16(a_l[mi], b_h[nj], acc[mi][nj], 0,0,0);
            }
    }
    const int fr = lane & 15, fq = lane >> 4;
    #pragma unroll
    for (int nj = 0; nj < 4; nj++){
        int col = n0 + wn*64 + nj*16 + fr;
        float bv = bias[col];
        #pragma unroll
        for (int mi = 0; mi < 4; mi++){
            int rbase = m0 + wm*64 + mi*16 + fq*4;
            #pragma unroll
            for (int j = 0; j < 4; j++){
                int row = rbase + j;
                if (row < M)
                    __builtin_nontemporal_store(acc[mi][nj][j] + bv, &C[(size_t)row*NDIM + col]);
            }
        }
    }
}

// ---------------- persistent LSTM layer ----------------
// 256 blocks x 256 threads. Block (hc=bx&31, bc=bx>>5): 16 hid x 8 batch outputs.
// KEY CHANGE (round 10): the block's 64x512 Whh slice lives in LDS (132 KB,
// stride 516 floats = odd*4 -> uniform 8-cycle ds_read_b128 distribution),
// NOT in 128 VGPRs of registers. Rounds 4-9 spilled part of w[] to scratch
// (VGPR_Count=256=max) and re-fetched ~21 MB/step from VRAM -- the invariant
// 1.05 GB FETCH_SIZE. LDS total 153 KB -> 1 block/CU (persistent design).
// h exchange protocol (unchanged from round 9, fence-free):
//   WRITE: gate threads put h(t) in LDS; wave-0 lanes 0..31 issue 32 x
//          global_store_dwordx4 sc0 sc1, drain vmcnt, tid0 sets epoch flag.
//   READ:  plain cached float4 loads (fresh per-step addresses; no stale copies).
//   Barrier: per bc-group (32 blocks) epoch flags, parallel-polled. Bounded spin.
__global__ __launch_bounds__(256, 1) void lstm_layer_k(
    const float* __restrict__ Xp,    // [T*64, 2048]
    const float* __restrict__ Whh,   // [2048, 512]
    const float* __restrict__ hinit, // [64, 512]
    const float* __restrict__ cinit, // [64, 512]
    float* __restrict__ ys,          // [T*64, 512]
    float* __restrict__ cfin,        // [64, 512]
    int T,
    unsigned* __restrict__ flagbase) // 8 groups x 32 members x 16 uints, zeroed
{
    __shared__ float wlds[64*516];   // 132,096 B: Whh slice, stride 516
    __shared__ f32x4 hs4[1024];      // 16 KB h(t-1); first 128 floats reused for h(t)
    __shared__ float red[4*64*8];    // 8 KB
    float* hs = (float*)hs4;

    const int bx  = blockIdx.x;
    const int hc  = bx & 31, bc = bx >> 5;
    const int hid0 = hc*16;
    const int tid = threadIdx.x;
    const int r   = tid & 63, kc = tid >> 6;
    unsigned* myflag = flagbase + (size_t)(bc*32 + hc)*16;

    // ---- Whh slice -> LDS (once per layer). local row lr: global row
    // grow = (lr>>4)*HID + hid0 + (lr&15); 128 float4 per row.
    #pragma unroll
    for (int it = 0; it < 32; it++){
        int fidx = tid + it*256;           // float4 index, 0..8191
        int lr   = fidx >> 7;              // 0..63
        int c4   = fidx & 127;
        int grow = (lr >> 4)*HID + hid0 + (lr & 15);
        f32x4 v = reinterpret_cast<const f32x4*>(Whh + (size_t)grow*HID)[c4];
        *reinterpret_cast<f32x4*>(&wlds[lr*516 + c4*4]) = v;
    }

    const int ub = tid >> 4;   // batch (tid<128)
    const int uh = tid & 15;   // hid
    float creg = 0.f;
    if (tid < 128) creg = cinit[(size_t)(bc*8 + ub)*HID + hid0 + uh];

    const size_t hbase = (size_t)bc*8*HID;
    const float* xprow = Xp + (size_t)(bc*8 + ub)*G4 + hid0 + uh;  // valid for tid<128
    const f32x4* wrow = reinterpret_cast<const f32x4*>(&wlds[r*516 + kc*128]);

    // prefetch Xp for t=0 (cached)
    float xn0=0.f, xn1=0.f, xn2=0.f, xn3=0.f;
    if (tid < 128){
        const float* xpr = xprow;
        xn0 = xpr[0]; xn1 = xpr[512]; xn2 = xpr[1024]; xn3 = xpr[1536];
    }

    for (int t = 0; t < T; t++){
        // ---- stage h(t-1) into LDS: plain cached loads ----
        {
            const f32x4* hsrc = reinterpret_cast<const f32x4*>(
                (t == 0) ? (hinit + hbase) : (ys + (size_t)(t-1)*BATCH*HID + hbase));
            f32x4 v0 = hsrc[tid], v1 = hsrc[tid+256], v2 = hsrc[tid+512], v3 = hsrc[tid+768];
            hs4[tid] = v0; hs4[tid+256] = v1; hs4[tid+512] = v2; hs4[tid+768] = v3;
        }
        __syncthreads();   // covers wlds (t=0) and hs (every t)

        // ---- partial dots: w-row slice (LDS) x 8 batch h-slices (LDS broadcast) ----
        float4 a4[8];
        #pragma unroll
        for (int b = 0; b < 8; b++) a4[b] = float4{0.f,0.f,0.f,0.f};
        const float4* h4 = reinterpret_cast<const float4*>(hs) + kc*32;
        #pragma unroll
        for (int j = 0; j < 32; j++){
            f32x4 a = wrow[j];
            #pragma unroll
            for (int b = 0; b < 8; b++){
                float4 hv = h4[b*128 + j];
                a4[b].x += a.x*hv.x; a4[b].y += a.y*hv.y;
                a4[b].z += a.z*hv.z; a4[b].w += a.w*hv.w;
            }
        }
        #pragma unroll
        for (int b = 0; b < 8; b++)
            red[(kc*64 + r)*8 + b] = a4[b].x + a4[b].y + a4[b].z + a4[b].w;
        __syncthreads();

        if (tid < 64){
            #pragma unroll
            for (int b = 0; b < 8; b++)
                red[tid*8 + b] = red[tid*8 + b] + red[(64+tid)*8 + b]
                               + red[(128+tid)*8 + b] + red[(192+tid)*8 + b];
        }
        __syncthreads();

        // ---- gates + state update; h(t) -> LDS; prefetch next Xp ----
        if (tid < 128){
            float gi = red[(0*16 + uh)*8 + ub] + xn0;
            float gf = red[(1*16 + uh)*8 + ub] + xn1;
            float gg = red[(2*16 + uh)*8 + ub] + xn2;
            float go = red[(3*16 + uh)*8 + ub] + xn3;
            float si = 1.f/(1.f + expf(-gi));
            float sf = 1.f/(1.f + expf(-gf));
            float so = 1.f/(1.f + expf(-go));
            float tg = tanhf(gg);
            float c = sf*creg + si*tg;
            creg = c;
            hs[tid] = so * tanhf(c);       // dot phase done with hs; safe to reuse
            if (t < T-1){
                const float* xpr = xprow + (size_t)(t+1)*BATCH*G4;
                xn0 = xpr[0]; xn1 = xpr[512]; xn2 = xpr[1024]; xn3 = xpr[1536];
            }
        }
        __syncthreads();

        // ---- wave 0: vectorized sc-store of h(t), drain, flag, poll ----
        if (tid < 64){
            if (tid < 32){
                f32x4 v = reinterpret_cast<const f32x4*>(hs)[tid];  // floats 4*tid..+3
                const f32x4* addr = reinterpret_cast<const f32x4*>(
                    ys + (size_t)t*BATCH*HID
                       + (size_t)(bc*8 + (tid >> 2))*HID + hid0 + (tid & 3)*4);
                asm volatile("global_store_dwordx4 %0, %1, off sc0 sc1"
                             :: "v"(addr), "v"(v) : "memory");
            }
            if (t < T-1){
                asm volatile("s_waitcnt vmcnt(0)" ::: "memory");  // h at coherence point
                if (tid == 0)
                    __hip_atomic_store(myflag, (unsigned)(t+1),
                                       __ATOMIC_RELAXED, __HIP_MEMORY_SCOPE_AGENT);
                const unsigned tgt = (unsigned)(t+1);
                unsigned* fp = flagbase + (size_t)(bc*32 + (tid & 31))*16;
                unsigned spins = 0;
                bool done = false;
                while (!done && spins < (1u<<20)){
                    unsigned v = tgt;
                    if (tid < 32)
                        v = __hip_atomic_load(fp, __ATOMIC_RELAXED, __HIP_MEMORY_SCOPE_AGENT);
                    done = (bool)__all((int)(v >= tgt));
                    spins++;
                }
            }
        }
        __syncthreads();   // all waves wait for poll before next stage
    }

    if (tid < 128)
        cfin[(size_t)(bc*8 + ub)*HID + hid0 + uh] = creg;
}

extern "C" void kernel_launch(void* const* d_in, const int* in_sizes, int n_in,
                              void* d_out, int out_size, void* d_ws, size_t ws_size,
                              hipStream_t stream) {
    const int*   src      = (const int*)  d_in[0];
    const int*   trg      = (const int*)  d_in[1];
    const float* enc_emb  = (const float*)d_in[2];
    const float* enc_Wih0 = (const float*)d_in[3];
    const float* enc_Whh0 = (const float*)d_in[4];
    const float* enc_b0   = (const float*)d_in[5];
    const float* enc_Wih1 = (const float*)d_in[6];
    const float* enc_Whh1 = (const float*)d_in[7];
    const float* enc_b1   = (const float*)d_in[8];
    const float* dec_emb  = (const float*)d_in[9];
    const float* dec_Wih0 = (const float*)d_in[10];
    const float* dec_Whh0 = (const float*)d_in[11];
    const float* dec_b0   = (const float*)d_in[12];
    const float* dec_Wih1 = (const float*)d_in[13];
    const float* dec_Whh1 = (const float*)d_in[14];
    const float* dec_b1   = (const float*)d_in[15];
    const float* out_W    = (const float*)d_in[16];
    const float* out_b    = (const float*)d_in[17];

    // Big transient scratch in d_out (fp32, 100.35M elems); all dead before final GEMM.
    float* ob = (float*)d_out;
    float* Xp   = ob;                         // [3200,2048]
    float* xe   = ob + (size_t)6553600;       // [3200,256]
    float* xd   = ob + (size_t)7372800;       // [3136,256]
    float* eys0 = ob + (size_t)8175616;       // [50*64,512]
    float* eys1 = ob + (size_t)9814016;       // [50*64,512]
    float* dys0 = ob + (size_t)11452416;      // [49*64,512]

    // d_ws: survivors + states + barrier flags (~7 MB).
    float* ws = (float*)d_ws;
    float* dys1 = ws;                              // [49*64,512]
    float* c0   = ws + (size_t)1605632;            // [64,512]
    float* c1   = ws + (size_t)1638400;            // [64,512]
    float* hz   = ws + (size_t)1671168;            // [64,512] zeros
    unsigned* flags = (unsigned*)(ws + (size_t)1703936); // 4 layers x 8 grp x 32 x 16 uints

    // zero c0,c1,hz + flags (re-zeroed every launch -> graph-replay safe)
    {
        int n = 3*BATCH*HID + 4*4096;
        zero_kernel<<<(n+255)/256, 256, 0, stream>>>(c0, n);
    }

    // embeddings
    embed_kernel<<<(50*BATCH*(EMB/4)+255)/256, 256, 0, stream>>>(src, enc_emb, xe, 50);
    embed_kernel<<<(49*BATCH*(EMB/4)+255)/256, 256, 0, stream>>>(trg, dec_emb, xd, 49);

    dim3 xgrid(G4/128, 25);

    // ---- encoder layer 0 ----
    gemm_mfma_split<EMB, G4><<<xgrid, 256, 0, stream>>>(xe, enc_Wih0, enc_b0, Xp, 3200);
    lstm_layer_k<<<256, 256, 0, stream>>>(Xp, enc_Whh0, hz, hz, eys0, c0, 50, flags + 0);

    // ---- encoder layer 1 ----
    gemm_mfma_split<HID, G4><<<xgrid, 256, 0, stream>>>(eys0, enc_Wih1, enc_b1, Xp, 3200);
    lstm_layer_k<<<256, 256, 0, stream>>>(Xp, enc_Whh1, hz, hz, eys1, c1, 50, flags + 4096);

    // ---- decoder layer 0 (h/c continue from encoder layer 0 finals) ----
    gemm_mfma_split<EMB, G4><<<xgrid, 256, 0, stream>>>(xd, dec_Wih0, dec_b0, Xp, 3136);
    lstm_layer_k<<<256, 256, 0, stream>>>(Xp, dec_Whh0, eys0 + (size_t)49*BATCH*HID, c0,
                                          dys0, c0, 49, flags + 8192);

    // ---- decoder layer 1 (h/c continue from encoder layer 1 finals) ----
    gemm_mfma_split<HID, G4><<<xgrid, 256, 0, stream>>>(dys0, dec_Wih1, dec_b1, Xp, 3136);
    lstm_layer_k<<<256, 256, 0, stream>>>(Xp, dec_Whh1, eys1 + (size_t)49*BATCH*HID, c1,
                                          dys1, c1, 49, flags + 12288);

    // ---- final projection -> fp32 d_out [3136, 32000] ----
    gemm_mfma_split<HID, VOCAB><<<dim3(VOCAB/128, 25), 256, 0, stream>>>(
        dys1, out_W, out_b, (float*)d_out, 3136);
}

// Round 11
// 1395.413 us; speedup vs baseline: 2.4224x; 1.3882x over previous
//
#include <hip/hip_runtime.h>
#include <hip/hip_bf16.h>

#define BATCH 64
#define HID 512
#define EMB 256
#define VOCAB 32000
#define G4 2048   // 4*HID

typedef __attribute__((ext_vector_type(8))) short short8;
typedef __attribute__((ext_vector_type(4))) float f32x4;
typedef __attribute__((ext_vector_type(4))) unsigned short ush4;

// ---------------- zero init ----------------
__global__ __launch_bounds__(256) void zero_kernel(float* p, int n){
    int i = blockIdx.x*256 + threadIdx.x;
    if (i < n) p[i] = 0.f;
}

// ---------------- embedding gather ----------------
__global__ __launch_bounds__(256) void embed_kernel(const int* __restrict__ tok,
                                                    const float* __restrict__ emb,
                                                    float* __restrict__ out, int T){
    int i = blockIdx.x*256 + threadIdx.x;
    int n = T*BATCH*(EMB/4);
    if (i >= n) return;
    int e4 = i % (EMB/4);
    int tb = i / (EMB/4);
    int id = tok[tb];
    reinterpret_cast<float4*>(out)[(size_t)tb*(EMB/4) + e4] =
        reinterpret_cast<const float4*>(emb + (size_t)id*EMB)[e4];
}

// round-to-nearest-even fp32 -> bf16 bits
__device__ __forceinline__ unsigned short bf16_rne(float x){
    unsigned b = __float_as_uint(x);
    return (unsigned short)((b + 0x7fffu + ((b >> 16) & 1u)) >> 16);
}
__device__ __forceinline__ void split2(float x, unsigned short& h, unsigned short& l){
    h = bf16_rne(x);
    l = bf16_rne(x - __uint_as_float((unsigned)h << 16));
}

// ---------------- fp32 -> bf16 hi/lo plane split (n mult of 4) ----------------
__global__ __launch_bounds__(256) void split_kernel(const float* __restrict__ in,
                                                    unsigned short* __restrict__ hi,
                                                    unsigned short* __restrict__ lo, int n4){
    int i = blockIdx.x*256 + threadIdx.x;
    if (i >= n4) return;
    f32x4 v = reinterpret_cast<const f32x4*>(in)[i];
    ush4 h, l;
    #pragma unroll
    for (int j = 0; j < 4; j++){ unsigned short a,b; split2(v[j], a, b); h[j]=a; l[j]=b; }
    reinterpret_cast<ush4*>(hi)[i] = h;
    reinterpret_cast<ush4*>(lo)[i] = l;
}

// ---------------- MFMA split GEMM, fp32 inputs w/ in-kernel conversion ----------------
// (used for the 4 Xp GEMMs + as fallback for the final GEMM)
template<int KDIM, int NDIM>
__global__ __launch_bounds__(256) void gemm_mfma_split(
    const float* __restrict__ A, const float* __restrict__ B,
    const float* __restrict__ bias, float* __restrict__ C, int M)
{
    constexpr int LS = 40;
    __shared__ unsigned short Ah[128*LS], Al[128*LS], Bh[128*LS], Bl[128*LS];
    const int n0 = blockIdx.x*128, m0 = blockIdx.y*128;
    const int tid  = threadIdx.x;
    const int lane = tid & 63, wid = tid >> 6;
    const int wm = wid >> 1, wn = wid & 1;
    const int srow = tid >> 1, sk = (tid & 1)*16;
    f32x4 acc[4][4] = {};

    for (int k0 = 0; k0 < KDIM; k0 += 32){
        __syncthreads();
        {
            int ar = m0 + srow;
            float xv[16];
            if (ar < M){
                const float4* ap = reinterpret_cast<const float4*>(A + (size_t)ar*KDIM + k0 + sk);
                #pragma unroll
                for (int q = 0; q < 4; q++){
                    float4 v = ap[q];
                    xv[q*4+0]=v.x; xv[q*4+1]=v.y; xv[q*4+2]=v.z; xv[q*4+3]=v.w;
                }
            } else {
                #pragma unroll
                for (int q = 0; q < 16; q++) xv[q] = 0.f;
            }
            #pragma unroll
            for (int q = 0; q < 16; q++){
                unsigned short h,l; split2(xv[q], h, l);
                Ah[srow*LS + sk + q] = h;
                Al[srow*LS + sk + q] = l;
            }
        }
        {
            int br = n0 + srow;
            const float4* bp = reinterpret_cast<const float4*>(B + (size_t)br*KDIM + k0 + sk);
            #pragma unroll
            for (int q = 0; q < 4; q++){
                float4 v = bp[q];
                float xs[4] = {v.x, v.y, v.z, v.w};
                #pragma unroll
                for (int j = 0; j < 4; j++){
                    unsigned short h,l; split2(xs[j], h, l);
                    Bh[srow*LS + sk + q*4 + j] = h;
                    Bl[srow*LS + sk + q*4 + j] = l;
                }
            }
        }
        __syncthreads();
        const int fr = lane & 15, fk = (lane >> 4)*8;
        short8 a_h[4], a_l[4], b_h[4], b_l[4];
        #pragma unroll
        for (int mi = 0; mi < 4; mi++){
            int row = wm*64 + mi*16 + fr;
            a_h[mi] = *reinterpret_cast<const short8*>(&Ah[row*LS + fk]);
            a_l[mi] = *reinterpret_cast<const short8*>(&Al[row*LS + fk]);
        }
        #pragma unroll
        for (int nj = 0; nj < 4; nj++){
            int rowb = wn*64 + nj*16 + fr;
            b_h[nj] = *reinterpret_cast<const short8*>(&Bh[rowb*LS + fk]);
            b_l[nj] = *reinterpret_cast<const short8*>(&Bl[rowb*LS + fk]);
        }
        #pragma unroll
        for (int mi = 0; mi < 4; mi++)
            #pragma unroll
            for (int nj = 0; nj < 4; nj++){
                acc[mi][nj] = __builtin_amdgcn_mfma_f32_16x16x32_bf16(a_h[mi], b_h[nj], acc[mi][nj], 0,0,0);
                acc[mi][nj] = __builtin_amdgcn_mfma_f32_16x16x32_bf16(a_h[mi], b_l[nj], acc[mi][nj], 0,0,0);
                acc[mi][nj] = __builtin_amdgcn_mfma_f32_16x16x32_bf16(a_l[mi], b_h[nj], acc[mi][nj], 0,0,0);
            }
    }
    const int fr = lane & 15, fq = lane >> 4;
    #pragma unroll
    for (int nj = 0; nj < 4; nj++){
        int col = n0 + wn*64 + nj*16 + fr;
        float bv = bias[col];
        #pragma unroll
        for (int mi = 0; mi < 4; mi++){
            int rbase = m0 + wm*64 + mi*16 + fq*4;
            #pragma unroll
            for (int j = 0; j < 4; j++){
                int row = rbase + j;
                if (row < M)
                    __builtin_nontemporal_store(acc[mi][nj][j] + bv, &C[(size_t)row*NDIM + col]);
            }
        }
    }
}

// ---------------- MFMA GEMM from pre-split bf16 planes (no conversion VALU) ----------------
// grid: (x = row tiles, y = col tiles) -> consecutive blocks share the B panel (L2 reuse).
template<int KDIM, int NDIM>
__global__ __launch_bounds__(256) void gemm_mfma_planes(
    const unsigned short* __restrict__ Ahi, const unsigned short* __restrict__ Alo,
    const unsigned short* __restrict__ Bhi, const unsigned short* __restrict__ Blo,
    const float* __restrict__ bias, float* __restrict__ C, int M)
{
    constexpr int LS = 40;
    __shared__ unsigned short Ah[128*LS], Al[128*LS], Bh[128*LS], Bl[128*LS];
    const int m0 = blockIdx.x*128, n0 = blockIdx.y*128;
    const int tid  = threadIdx.x;
    const int lane = tid & 63, wid = tid >> 6;
    const int wm = wid >> 1, wn = wid & 1;
    f32x4 acc[4][4] = {};
    const short8 zero8 = {0,0,0,0,0,0,0,0};

    for (int k0 = 0; k0 < KDIM; k0 += 32){
        __syncthreads();
        // stage 4 planes: 512 chunks (8 bf16) each; 8 chunks/thread, pure copies
        #pragma unroll
        for (int half = 0; half < 2; half++){
            int c = tid + half*256;
            int row = c >> 2, k8 = (c & 3)*8;
            size_t goffB = (size_t)(n0+row)*KDIM + k0 + k8;
            *reinterpret_cast<short8*>(&Bh[row*LS + k8]) =
                *reinterpret_cast<const short8*>(&Bhi[goffB]);
            *reinterpret_cast<short8*>(&Bl[row*LS + k8]) =
                *reinterpret_cast<const short8*>(&Blo[goffB]);
            int ar = m0 + row;
            if (ar < M){
                size_t goffA = (size_t)ar*KDIM + k0 + k8;
                *reinterpret_cast<short8*>(&Ah[row*LS + k8]) =
                    *reinterpret_cast<const short8*>(&Ahi[goffA]);
                *reinterpret_cast<short8*>(&Al[row*LS + k8]) =
                    *reinterpret_cast<const short8*>(&Alo[goffA]);
            } else {
                *reinterpret_cast<short8*>(&Ah[row*LS + k8]) = zero8;
                *reinterpret_cast<short8*>(&Al[row*LS + k8]) = zero8;
            }
        }
        __syncthreads();
        const int fr = lane & 15, fk = (lane >> 4)*8;
        short8 a_h[4], a_l[4], b_h[4], b_l[4];
        #pragma unroll
        for (int mi = 0; mi < 4; mi++){
            int row = wm*64 + mi*16 + fr;
            a_h[mi] = *reinterpret_cast<const short8*>(&Ah[row*LS + fk]);
            a_l[mi] = *reinterpret_cast<const short8*>(&Al[row*LS + fk]);
        }
        #pragma unroll
        for (int nj = 0; nj < 4; nj++){
            int rowb = wn*64 + nj*16 + fr;
            b_h[nj] = *reinterpret_cast<const short8*>(&Bh[rowb*LS + fk]);
            b_l[nj] = *reinterpret_cast<const short8*>(&Bl[rowb*LS + fk]);
        }
        #pragma unroll
        for (int mi = 0; mi < 4; mi++)
            #pragma unroll
            for (int nj = 0; nj < 4; nj++){
                acc[mi][nj] = __builtin_amdgcn_mfma_f32_16x16x32_bf16(a_h[mi], b_h[nj], acc[mi][nj], 0,0,0);
                acc[mi][nj] = __builtin_amdgcn_mfma_f32_16x16x32_bf16(a_h[mi], b_l[nj], acc[mi][nj], 0,0,0);
                acc[mi][nj] = __builtin_amdgcn_mfma_f32_16x16x32_bf16(a_l[mi], b_h[nj], acc[mi][nj], 0,0,0);
            }
    }
    const int fr = lane & 15, fq = lane >> 4;
    #pragma unroll
    for (int nj = 0; nj < 4; nj++){
        int col = n0 + wn*64 + nj*16 + fr;
        float bv = bias[col];
        #pragma unroll
        for (int mi = 0; mi < 4; mi++){
            int rbase = m0 + wm*64 + mi*16 + fq*4;
            #pragma unroll
            for (int j = 0; j < 4; j++){
                int row = rbase + j;
                if (row < M)
                    __builtin_nontemporal_store(acc[mi][nj][j] + bv, &C[(size_t)row*NDIM + col]);
            }
        }
    }
}

// ---------------- persistent LSTM layer (MFMA dot) ----------------
// 256 blocks x 256 threads. Block (hc=bx&31, bc=bx>>5): 16 hid x 8 batch.
// Whh slice in LDS as bf16 hi/lo planes (split-bf16 3-pass = ~fp32 fidelity).
// Per step: stage h (cached fp32 loads) -> convert to bf16 hi/lo in LDS ->
// each wave: 48 MFMA (4 m-frags x 4 k-steps x 3 passes) over its 128-k slice ->
// scatter partials to red (same layout as VALU version) -> reduce -> gates ->
// h via red[512..640) -> wave0 sc-stores h, flag, parallel-poll (round-10 protocol).
__global__ __launch_bounds__(256, 1) void lstm_layer_k(
    const float* __restrict__ Xp,    // [T*64, 2048]
    const float* __restrict__ Whh,   // [2048, 512]
    const float* __restrict__ hinit, // [64, 512]
    const float* __restrict__ cinit, // [64, 512]
    float* __restrict__ ys,          // [T*64, 512]
    float* __restrict__ cfin,        // [64, 512]
    int T,
    unsigned* __restrict__ flagbase) // 8 groups x 32 members x 16 uints, zeroed
{
    constexpr int WS = 520;          // bf16 row stride (512 + 8 pad)
    __shared__ unsigned short wH[64*WS], wL[64*WS];   // 66,560 B each
    __shared__ unsigned short hH[8*WS], hL[8*WS];     // 8,320 B each
    __shared__ float red[2048 + 128];                 // partials + h out (8.7 KB)
    __shared__ unsigned short zbuf[8];                // zero B-frag for batch rows 8..15

    const int bx  = blockIdx.x;
    const int hc  = bx & 31, bc = bx >> 5;
    const int hid0 = hc*16;
    const int tid = threadIdx.x;
    const int lane = tid & 63, kc = tid >> 6;   // kc = wave = k-slice
    unsigned* myflag = flagbase + (size_t)(bc*32 + hc)*16;

    if (tid < 8) zbuf[tid] = 0;

    // ---- Whh slice -> LDS bf16 hi/lo (once). local row lr -> global row
    // (lr>>4)*HID + hid0 + (lr&15); 128 f32x4 per row.
    #pragma unroll
    for (int it = 0; it < 32; it++){
        int fidx = tid + it*256;           // f32x4 index 0..8191
        int lr   = fidx >> 7;              // 0..63
        int c4   = fidx & 127;
        int grow = (lr >> 4)*HID + hid0 + (lr & 15);
        f32x4 v = reinterpret_cast<const f32x4*>(Whh + (size_t)grow*HID)[c4];
        ush4 h, l;
        #pragma unroll
        for (int j = 0; j < 4; j++){ unsigned short a,b; split2(v[j], a, b); h[j]=a; l[j]=b; }
        *reinterpret_cast<ush4*>(&wH[lr*WS + c4*4]) = h;
        *reinterpret_cast<ush4*>(&wL[lr*WS + c4*4]) = l;
    }

    const int ub = tid >> 4;   // batch (tid<128)
    const int uh = tid & 15;   // hid
    float creg = 0.f;
    if (tid < 128) creg = cinit[(size_t)(bc*8 + ub)*HID + hid0 + uh];

    const size_t hbase = (size_t)bc*8*HID;
    const float* xprow = Xp + (size_t)(bc*8 + ub)*G4 + hid0 + uh;

    float xn0=0.f, xn1=0.f, xn2=0.f, xn3=0.f;
    if (tid < 128){
        const float* xpr = xprow;
        xn0 = xpr[0]; xn1 = xpr[512]; xn2 = xpr[1024]; xn3 = xpr[1536];
    }

    for (int t = 0; t < T; t++){
        // ---- stage h(t-1): cached fp32 loads -> bf16 hi/lo LDS ----
        {
            const f32x4* hsrc = reinterpret_cast<const f32x4*>(
                (t == 0) ? (hinit + hbase) : (ys + (size_t)(t-1)*BATCH*HID + hbase));
            #pragma unroll
            for (int j = 0; j < 4; j++){
                int fidx = tid + j*256;        // f32x4 idx 0..1023
                f32x4 v = hsrc[fidx];
                int e   = fidx*4;
                int row = e >> 9, col = e & 511;
                ush4 h, l;
                #pragma unroll
                for (int q = 0; q < 4; q++){ unsigned short a,b; split2(v[q], a, b); h[q]=a; l[q]=b; }
                *reinterpret_cast<ush4*>(&hH[row*WS + col]) = h;
                *reinterpret_cast<ush4*>(&hL[row*WS + col]) = l;
            }
        }
        __syncthreads();

        // ---- MFMA partial dots over this wave's 128-k slice ----
        {
            f32x4 acc[4] = {};
            const int fr = lane & 15, fkq = lane >> 4;   // fr: A row / B row; fkq: k quarter
            const bool breal = fr < 8;
            #pragma unroll
            for (int s = 0; s < 4; s++){
                int k0 = kc*128 + s*32 + fkq*8;
                short8 bh = breal ? *reinterpret_cast<const short8*>(&hH[fr*WS + k0])
                                  : *reinterpret_cast<const short8*>(zbuf);
                short8 bl = breal ? *reinterpret_cast<const short8*>(&hL[fr*WS + k0])
                                  : *reinterpret_cast<const short8*>(zbuf);
                #pragma unroll
                for (int m = 0; m < 4; m++){
                    short8 ah = *reinterpret_cast<const short8*>(&wH[(m*16+fr)*WS + k0]);
                    short8 al = *reinterpret_cast<const short8*>(&wL[(m*16+fr)*WS + k0]);
                    acc[m] = __builtin_amdgcn_mfma_f32_16x16x32_bf16(ah, bh, acc[m], 0,0,0);
                    acc[m] = __builtin_amdgcn_mfma_f32_16x16x32_bf16(ah, bl, acc[m], 0,0,0);
                    acc[m] = __builtin_amdgcn_mfma_f32_16x16x32_bf16(al, bh, acc[m], 0,0,0);
                }
            }
            // scatter: C row = m*16 + (lane>>4)*4 + q, col(batch) = lane&15 (keep <8)
            const int b = lane & 15;
            if (b < 8){
                #pragma unroll
                for (int m = 0; m < 4; m++)
                    #pragma unroll
                    for (int q = 0; q < 4; q++){
                        int rowp = m*16 + (lane >> 4)*4 + q;
                        red[kc*512 + rowp*8 + b] = acc[m][q];
                    }
            }
        }
        __syncthreads();

        // ---- k-reduce across the 4 waves ----
        if (tid < 64){
            #pragma unroll
            for (int b = 0; b < 8; b++)
                red[tid*8 + b] = red[tid*8 + b] + red[512 + tid*8 + b]
                               + red[1024 + tid*8 + b] + red[1536 + tid*8 + b];
        }
        __syncthreads();

        // ---- gates + state; h -> red[2048+tid]; prefetch next Xp ----
        if (tid < 128){
            float gi = red[(0*16 + uh)*8 + ub] + xn0;
            float gf = red[(1*16 + uh)*8 + ub] + xn1;
            float gg = red[(2*16 + uh)*8 + ub] + xn2;
            float go = red[(3*16 + uh)*8 + ub] + xn3;
            float si = 1.f/(1.f + expf(-gi));
            float sf = 1.f/(1.f + expf(-gf));
            float so = 1.f/(1.f + expf(-go));
            float tg = tanhf(gg);
            float c = sf*creg + si*tg;
            creg = c;
            red[2048 + tid] = so * tanhf(c);
            if (t < T-1){
                const float* xpr = xprow + (size_t)(t+1)*BATCH*G4;
                xn0 = xpr[0]; xn1 = xpr[512]; xn2 = xpr[1024]; xn3 = xpr[1536];
            }
        }
        __syncthreads();

        // ---- wave 0: vectorized sc-store of h(t), drain, flag, poll ----
        if (tid < 64){
            if (tid < 32){
                f32x4 v = *reinterpret_cast<const f32x4*>(&red[2048 + tid*4]);
                const f32x4* addr = reinterpret_cast<const f32x4*>(
                    ys + (size_t)t*BATCH*HID
                       + (size_t)(bc*8 + (tid >> 2))*HID + hid0 + (tid & 3)*4);
                asm volatile("global_store_dwordx4 %0, %1, off sc0 sc1"
                             :: "v"(addr), "v"(v) : "memory");
            }
            if (t < T-1){
                asm volatile("s_waitcnt vmcnt(0)" ::: "memory");
                if (tid == 0)
                    __hip_atomic_store(myflag, (unsigned)(t+1),
                                       __ATOMIC_RELAXED, __HIP_MEMORY_SCOPE_AGENT);
                const unsigned tgt = (unsigned)(t+1);
                unsigned* fp = flagbase + (size_t)(bc*32 + (tid & 31))*16;
                unsigned spins = 0;
                bool done = false;
                while (!done && spins < (1u<<20)){
                    unsigned v = tgt;
                    if (tid < 32)
                        v = __hip_atomic_load(fp, __ATOMIC_RELAXED, __HIP_MEMORY_SCOPE_AGENT);
                    done = (bool)__all((int)(v >= tgt));
                    spins++;
                }
            }
        }
        __syncthreads();
    }

    if (tid < 128)
        cfin[(size_t)(bc*8 + ub)*HID + hid0 + uh] = creg;
}

extern "C" void kernel_launch(void* const* d_in, const int* in_sizes, int n_in,
                              void* d_out, int out_size, void* d_ws, size_t ws_size,
                              hipStream_t stream) {
    const int*   src      = (const int*)  d_in[0];
    const int*   trg      = (const int*)  d_in[1];
    const float* enc_emb  = (const float*)d_in[2];
    const float* enc_Wih0 = (const float*)d_in[3];
    const float* enc_Whh0 = (const float*)d_in[4];
    const float* enc_b0   = (const float*)d_in[5];
    const float* enc_Wih1 = (const float*)d_in[6];
    const float* enc_Whh1 = (const float*)d_in[7];
    const float* enc_b1   = (const float*)d_in[8];
    const float* dec_emb  = (const float*)d_in[9];
    const float* dec_Wih0 = (const float*)d_in[10];
    const float* dec_Whh0 = (const float*)d_in[11];
    const float* dec_b0   = (const float*)d_in[12];
    const float* dec_Wih1 = (const float*)d_in[13];
    const float* dec_Whh1 = (const float*)d_in[14];
    const float* dec_b1   = (const float*)d_in[15];
    const float* out_W    = (const float*)d_in[16];
    const float* out_b    = (const float*)d_in[17];

    // Big transient scratch in d_out (fp32, 100.35M elems); all dead before final GEMM.
    float* ob = (float*)d_out;
    float* Xp   = ob;                         // [3200,2048]
    float* xe   = ob + (size_t)6553600;       // [3200,256]
    float* xd   = ob + (size_t)7372800;       // [3136,256]
    float* eys0 = ob + (size_t)8175616;       // [50*64,512]
    float* eys1 = ob + (size_t)9814016;       // [50*64,512]
    float* dys0 = ob + (size_t)11452416;      // [49*64,512]

    // d_ws: survivors + states + flags + (fast path) bf16 planes.
    float* ws = (float*)d_ws;
    float* dys1 = ws;                              // [49*64,512] = 1,605,632
    float* c0   = ws + (size_t)1605632;            // [64,512]
    float* c1   = ws + (size_t)1638400;            // [64,512]
    float* hz   = ws + (size_t)1671168;            // [64,512] zeros
    unsigned* flags = (unsigned*)(ws + (size_t)1703936); // 16384 uints
    unsigned short* Whi = (unsigned short*)(ws + (size_t)1720320);
    unsigned short* Wlo = Whi + (size_t)16384000;  // 32000*512
    unsigned short* Ahi = Wlo + (size_t)16384000;
    unsigned short* Alo = Ahi + (size_t)1605632;   // 3136*512
    const size_t ws_needed = (size_t)1720320*4 + ((size_t)16384000*2 + (size_t)1605632*2)*2;
    const bool planes_ok = (ws_size >= ws_needed);

    // zero c0,c1,hz + flags
    {
        int n = 3*BATCH*HID + 4*4096;
        zero_kernel<<<(n+255)/256, 256, 0, stream>>>(c0, n);
    }

    // pre-split out_W into bf16 planes (independent of everything else)
    if (planes_ok)
        split_kernel<<<(16384000/4 + 255)/256, 256, 0, stream>>>(out_W, Whi, Wlo, 16384000/4);

    // embeddings
    embed_kernel<<<(50*BATCH*(EMB/4)+255)/256, 256, 0, stream>>>(src, enc_emb, xe, 50);
    embed_kernel<<<(49*BATCH*(EMB/4)+255)/256, 256, 0, stream>>>(trg, dec_emb, xd, 49);

    dim3 xgrid(G4/128, 25);

    // ---- encoder layer 0 ----
    gemm_mfma_split<EMB, G4><<<xgrid, 256, 0, stream>>>(xe, enc_Wih0, enc_b0, Xp, 3200);
    lstm_layer_k<<<256, 256, 0, stream>>>(Xp, enc_Whh0, hz, hz, eys0, c0, 50, flags + 0);

    // ---- encoder layer 1 ----
    gemm_mfma_split<HID, G4><<<xgrid, 256, 0, stream>>>(eys0, enc_Wih1, enc_b1, Xp, 3200);
    lstm_layer_k<<<256, 256, 0, stream>>>(Xp, enc_Whh1, hz, hz, eys1, c1, 50, flags + 4096);

    // ---- decoder layer 0 ----
    gemm_mfma_split<EMB, G4><<<xgrid, 256, 0, stream>>>(xd, dec_Wih0, dec_b0, Xp, 3136);
    lstm_layer_k<<<256, 256, 0, stream>>>(Xp, dec_Whh0, eys0 + (size_t)49*BATCH*HID, c0,
                                          dys0, c0, 49, flags + 8192);

    // ---- decoder layer 1 ----
    gemm_mfma_split<HID, G4><<<xgrid, 256, 0, stream>>>(dys0, dec_Wih1, dec_b1, Xp, 3136);
    lstm_layer_k<<<256, 256, 0, stream>>>(Xp, dec_Whh1, eys1 + (size_t)49*BATCH*HID, c1,
                                          dys1, c1, 49, flags + 12288);

    // ---- final projection -> fp32 d_out [3136, 32000] ----
    if (planes_ok){
        split_kernel<<<(1605632/4 + 255)/256, 256, 0, stream>>>(dys1, Ahi, Alo, 1605632/4);
        gemm_mfma_planes<HID, VOCAB><<<dim3(25, VOCAB/128), 256, 0, stream>>>(
            Ahi, Alo, Whi, Wlo, out_b, (float*)d_out, 3136);
    } else {
        gemm_mfma_split<HID, VOCAB><<<dim3(VOCAB/128, 25), 256, 0, stream>>>(
            dys1, out_W, out_b, (float*)d_out, 3136);
    }
}